// Round 1
// baseline (2551.358 us; speedup 1.0000x reference)
//
#include <hip/hip_runtime.h>
#include <math.h>

// ---------------------------------------------------------------------------
// Problem: N=64, L=128, W=256, D=384, H=8, E=48, NL=4, DFF=1536
// rows = N*L = 8192
// ---------------------------------------------------------------------------

// ---------------- positional encoding table: pe[l][d], l<128, d<384 --------
__global__ __launch_bounds__(384) void pe_kernel(float* __restrict__ pe) {
    int l = blockIdx.x, d = threadIdx.x;
    int i2 = d >> 1;
    float ang = (float)l * expf(-(2.0f * (float)i2 / 384.0f) * 9.210340371976184f);
    pe[l * 384 + d] = (d & 1) ? cosf(ang) : sinf(ang);
}

// ---------------- fused CNN window encoder ---------------------------------
// one block (256 thr) per window; all stages in LDS
__global__ __launch_bounds__(256) void cnn_kernel(
    const float* __restrict__ x,
    const float* __restrict__ w0, const float* __restrict__ b0,
    const float* __restrict__ w1, const float* __restrict__ b1,
    const float* __restrict__ w2, const float* __restrict__ b2,
    float* __restrict__ feat)
{
    __shared__ float xs[256];
    __shared__ float a0[4][256];
    __shared__ float p0[4][129];
    __shared__ float a1[16][129];
    __shared__ float p1[16][65];
    __shared__ float a2[64][65];
    __shared__ float w2s[16][7][64];   // [ci][k][c] transposed for broadcast reads
    __shared__ float w1s[64][7];       // [(c*4+ci)][k]
    __shared__ float w0s[4][7];

    int tid = threadIdx.x;
    int win = blockIdx.x;

    xs[tid] = x[(size_t)win * 256 + tid];
    if (tid < 28) ((float*)w0s)[tid] = w0[tid];
    if (tid < 64) {
        for (int k = 0; k < 7; ++k) w1s[tid][k] = w1[tid * 7 + k];
    }
    for (int idx = tid; idx < 7168; idx += 256) {
        int c = idx / 112;
        int r = idx - c * 112;
        int ci = r / 7;
        int k = r - ci * 7;
        w2s[ci][k][c] = w2[idx];
    }
    __syncthreads();

    // conv0: 1 -> 4 ch, len 256
    #pragma unroll
    for (int r = 0; r < 4; ++r) {
        int c = r, i = tid;
        float acc = b0[c];
        #pragma unroll
        for (int k = 0; k < 7; ++k) {
            int j = i + k - 3;
            float v = (j >= 0 && j < 256) ? xs[j] : 0.f;
            acc = fmaf(w0s[c][k], v, acc);
        }
        a0[c][i] = fmaxf(acc, 0.f);
    }
    __syncthreads();
    // pool0 -> 4x128
    #pragma unroll
    for (int r = 0; r < 2; ++r) {
        int idx = tid + 256 * r;
        int c = idx >> 7, j = idx & 127;
        p0[c][j] = fmaxf(a0[c][2 * j], a0[c][2 * j + 1]);
    }
    __syncthreads();
    // conv1: 4 -> 16 ch, len 128.  thread: c = tid/16, i0 = (tid%16)*8
    {
        int c = tid >> 4;
        int i0 = (tid & 15) * 8;
        float acc[8];
        float bb = b1[c];
        #pragma unroll
        for (int m = 0; m < 8; ++m) acc[m] = bb;
        #pragma unroll
        for (int ci = 0; ci < 4; ++ci) {
            float rv[14];
            #pragma unroll
            for (int u = 0; u < 14; ++u) {
                int j = i0 + u - 3;
                rv[u] = (j >= 0 && j < 128) ? p0[ci][j] : 0.f;
            }
            #pragma unroll
            for (int k = 0; k < 7; ++k) {
                float w = w1s[c * 4 + ci][k];
                #pragma unroll
                for (int m = 0; m < 8; ++m) acc[m] = fmaf(w, rv[m + k], acc[m]);
            }
        }
        #pragma unroll
        for (int m = 0; m < 8; ++m) a1[c][i0 + m] = fmaxf(acc[m], 0.f);
    }
    __syncthreads();
    // pool1 -> 16x64
    #pragma unroll
    for (int r = 0; r < 4; ++r) {
        int idx = tid + 256 * r;
        int c = idx >> 6, j = idx & 63;
        p1[c][j] = fmaxf(a1[c][2 * j], a1[c][2 * j + 1]);
    }
    __syncthreads();
    // conv2: 16 -> 64 ch, len 64.  thread: c = tid/4, i0 = (tid%4)*16
    {
        int c = tid >> 2;
        int i0 = (tid & 3) * 16;
        float acc[16];
        float bb = b2[c];
        #pragma unroll
        for (int m = 0; m < 16; ++m) acc[m] = bb;
        for (int ci = 0; ci < 16; ++ci) {
            float rv[22];
            #pragma unroll
            for (int u = 0; u < 22; ++u) {
                int j = i0 + u - 3;
                rv[u] = (j >= 0 && j < 64) ? p1[ci][j] : 0.f;
            }
            #pragma unroll
            for (int k = 0; k < 7; ++k) {
                float w = w2s[ci][k][c];
                #pragma unroll
                for (int m = 0; m < 16; ++m) acc[m] = fmaf(w, rv[m + k], acc[m]);
            }
        }
        #pragma unroll
        for (int m = 0; m < 16; ++m) a2[c][i0 + m] = fmaxf(acc[m], 0.f);
    }
    __syncthreads();
    // pool2 -> 64x32, flatten (c*32+j) and store
    #pragma unroll
    for (int r = 0; r < 8; ++r) {
        int idx = tid + 256 * r;
        int c = idx >> 5, j = idx & 31;
        feat[(size_t)win * 2048 + idx] = fmaxf(a2[c][2 * j], a2[c][2 * j + 1]);
    }
}

// ---------------- generic fp32 GEMM, 64x64 tile, BK=16, 4x4 per thread -----
// EPI bits: 1 = relu, 2 = residual add, 4 = add positional encoding
template <int EPI>
__global__ __launch_bounds__(256) void gemm_f32(
    const float* __restrict__ A, const float* __restrict__ B,
    const float* __restrict__ bias, const float* __restrict__ resid,
    const float* __restrict__ pe, float* __restrict__ C,
    int M, int N, int K)
{
    __shared__ float As[16][68];
    __shared__ float Bs[16][68];
    int tid = threadIdx.x;
    int n0 = blockIdx.x * 64;
    int m0 = blockIdx.y * 64;
    int ma = tid >> 2, ka = (tid & 3) << 2;
    int kb = tid >> 4, nb = (tid & 15) << 2;
    int tm = (tid >> 4) << 2, tn = (tid & 15) << 2;
    float acc[4][4] = {};
    const float* Aptr = A + (size_t)(m0 + ma) * K + ka;
    const float* Bptr = B + (size_t)kb * N + n0 + nb;

    for (int k0 = 0; k0 < K; k0 += 16) {
        float4 av = *(const float4*)(Aptr + k0);
        float4 bv = *(const float4*)(Bptr + (size_t)k0 * N);
        As[ka + 0][ma] = av.x;
        As[ka + 1][ma] = av.y;
        As[ka + 2][ma] = av.z;
        As[ka + 3][ma] = av.w;
        *(float4*)(&Bs[kb][nb]) = bv;
        __syncthreads();
        #pragma unroll
        for (int kk = 0; kk < 16; ++kk) {
            float4 a = *(const float4*)(&As[kk][tm]);
            float4 b = *(const float4*)(&Bs[kk][tn]);
            acc[0][0] = fmaf(a.x, b.x, acc[0][0]);
            acc[0][1] = fmaf(a.x, b.y, acc[0][1]);
            acc[0][2] = fmaf(a.x, b.z, acc[0][2]);
            acc[0][3] = fmaf(a.x, b.w, acc[0][3]);
            acc[1][0] = fmaf(a.y, b.x, acc[1][0]);
            acc[1][1] = fmaf(a.y, b.y, acc[1][1]);
            acc[1][2] = fmaf(a.y, b.z, acc[1][2]);
            acc[1][3] = fmaf(a.y, b.w, acc[1][3]);
            acc[2][0] = fmaf(a.z, b.x, acc[2][0]);
            acc[2][1] = fmaf(a.z, b.y, acc[2][1]);
            acc[2][2] = fmaf(a.z, b.z, acc[2][2]);
            acc[2][3] = fmaf(a.z, b.w, acc[2][3]);
            acc[3][0] = fmaf(a.w, b.x, acc[3][0]);
            acc[3][1] = fmaf(a.w, b.y, acc[3][1]);
            acc[3][2] = fmaf(a.w, b.z, acc[3][2]);
            acc[3][3] = fmaf(a.w, b.w, acc[3][3]);
        }
        __syncthreads();
    }

    #pragma unroll
    for (int i = 0; i < 4; ++i) {
        int row = m0 + tm + i;
        #pragma unroll
        for (int j = 0; j < 4; ++j) {
            int col = n0 + tn + j;
            float v = acc[i][j] + bias[col];
            if (EPI & 1) v = fmaxf(v, 0.f);
            if (EPI & 4) v += pe[(row & 127) * 384 + col];
            if (EPI & 2) v += resid[(size_t)row * N + col];
            C[(size_t)row * N + col] = v;
        }
    }
}

// ---------------- fused attention per (n,h): online softmax ----------------
// NOTE: o may alias q (each block reads its own q slice into regs first,
// writes only its own slice at the end) -> no __restrict__ on q/o.
__global__ __launch_bounds__(128) void attn_kernel(
    const float* q, const float* __restrict__ k,
    const float* __restrict__ v, float* o)
{
    __shared__ float Ks[128][48];
    __shared__ float Vs[128][48];
    int tid = threadIdx.x;
    int n = blockIdx.x >> 3, h = blockIdx.x & 7;
    size_t base = (size_t)n * 128 * 384 + (size_t)h * 48;
    for (int idx = tid; idx < 6144; idx += 128) {
        int s = idx / 48, e = idx - s * 48;
        Ks[s][e] = k[base + (size_t)s * 384 + e];
        Vs[s][e] = v[base + (size_t)s * 384 + e];
    }
    float qr[48];
    const float* qp = q + base + (size_t)tid * 384;
    #pragma unroll
    for (int e = 0; e < 48; ++e) qr[e] = qp[e];
    __syncthreads();

    float m = -1e30f, denom = 0.f;
    float acc[48];
    #pragma unroll
    for (int e = 0; e < 48; ++e) acc[e] = 0.f;
    const float temp = 0.14433756729740643f;  // 1/sqrt(48)
    for (int s = 0; s < 128; ++s) {
        float sc = 0.f;
        #pragma unroll
        for (int e = 0; e < 48; ++e) sc = fmaf(qr[e], Ks[s][e], sc);
        sc *= temp;
        float nm = fmaxf(m, sc);
        float alpha = __expf(m - nm);
        float p = __expf(sc - nm);
        denom = denom * alpha + p;
        #pragma unroll
        for (int e = 0; e < 48; ++e) acc[e] = fmaf(p, Vs[s][e], acc[e] * alpha);
        m = nm;
    }
    float inv = 1.f / denom;
    float* op = o + base + (size_t)tid * 384;
    #pragma unroll
    for (int e = 0; e < 48; ++e) op[e] = acc[e] * inv;
}

// ---------------- LayerNorm (wave per row, D=384) --------------------------
__global__ __launch_bounds__(256) void ln_kernel(
    const float* __restrict__ y, const float* __restrict__ g,
    const float* __restrict__ b, float* __restrict__ t)
{
    int row = blockIdx.x * 4 + (threadIdx.x >> 6);
    int lane = threadIdx.x & 63;
    const float* yr = y + (size_t)row * 384;
    float vals[6];
    float s = 0.f, s2 = 0.f;
    #pragma unroll
    for (int mi = 0; mi < 6; ++mi) {
        float vv = yr[lane + mi * 64];
        vals[mi] = vv;
        s += vv;
        s2 = fmaf(vv, vv, s2);
    }
    #pragma unroll
    for (int off = 32; off > 0; off >>= 1) {
        s += __shfl_xor(s, off, 64);
        s2 += __shfl_xor(s2, off, 64);
    }
    float mean = s * (1.f / 384.f);
    float var = s2 * (1.f / 384.f) - mean * mean;
    float inv = rsqrtf(var + 1e-5f);
    float* tr = t + (size_t)row * 384;
    #pragma unroll
    for (int mi = 0; mi < 6; ++mi) {
        int d = lane + mi * 64;
        tr[d] = (vals[mi] - mean) * inv * g[d] + b[d];
    }
}

// ---------------- classifier head: mean over L then dot with cls_w ---------
__global__ __launch_bounds__(384) void head_kernel(
    const float* __restrict__ t, const float* __restrict__ cls_w,
    const float* __restrict__ cls_b, float* __restrict__ out)
{
    int n = blockIdx.x, d = threadIdx.x;
    float s = 0.f;
    for (int l = 0; l < 128; ++l) s += t[((size_t)n * 128 + l) * 384 + d];
    float p = s * (1.f / 128.f) * cls_w[d];
    #pragma unroll
    for (int off = 32; off > 0; off >>= 1) p += __shfl_xor(p, off, 64);
    __shared__ float red[6];
    if ((threadIdx.x & 63) == 0) red[threadIdx.x >> 6] = p;
    __syncthreads();
    if (threadIdx.x == 0) {
        float tot = red[0] + red[1] + red[2] + red[3] + red[4] + red[5];
        out[n] = tot + cls_b[0];
    }
}

// ---------------------------------------------------------------------------
extern "C" void kernel_launch(void* const* d_in, const int* in_sizes, int n_in,
                              void* d_out, int out_size, void* d_ws, size_t ws_size,
                              hipStream_t stream) {
    (void)n_in; (void)out_size; (void)ws_size;
    const float* x   = (const float*)d_in[0];
    const float* cw0 = (const float*)d_in[1];
    const float* cb0 = (const float*)d_in[2];
    const float* cw1 = (const float*)d_in[3];
    const float* cb1 = (const float*)d_in[4];
    const float* cw2 = (const float*)d_in[5];
    const float* cb2 = (const float*)d_in[6];
    const float* ew  = (const float*)d_in[7];
    const float* eb  = (const float*)d_in[8];
    // setup_inputs() dict order vs reference signature order: disambiguate by size
    bool dict_order = (in_sizes[10] == 589824);
    const float *Wq, *Wk, *Wv, *Wo, *W1, *W2, *bq, *bk, *bv, *bo, *b1, *b2;
    if (dict_order) {
        Wq = (const float*)d_in[9];  Wk = (const float*)d_in[10];
        Wv = (const float*)d_in[11]; Wo = (const float*)d_in[12];
        W1 = (const float*)d_in[13]; W2 = (const float*)d_in[14];
        bq = (const float*)d_in[15]; bk = (const float*)d_in[16];
        bv = (const float*)d_in[17]; bo = (const float*)d_in[18];
        b1 = (const float*)d_in[19]; b2 = (const float*)d_in[20];
    } else {
        Wq = (const float*)d_in[9];  bq = (const float*)d_in[10];
        Wk = (const float*)d_in[11]; bk = (const float*)d_in[12];
        Wv = (const float*)d_in[13]; bv = (const float*)d_in[14];
        Wo = (const float*)d_in[15]; bo = (const float*)d_in[16];
        W1 = (const float*)d_in[17]; b1 = (const float*)d_in[18];
        W2 = (const float*)d_in[19]; b2 = (const float*)d_in[20];
    }
    const float* g1  = (const float*)d_in[21];
    const float* be1 = (const float*)d_in[22];
    const float* g2  = (const float*)d_in[23];
    const float* be2 = (const float*)d_in[24];
    const float* clw = (const float*)d_in[25];
    const float* clb = (const float*)d_in[26];

    // workspace layout (floats)
    float* ws   = (float*)d_ws;
    float* pe   = ws;                   // 128*384          =     49,152
    float* feat = pe + 49152;           // 8192*2048        = 16,777,216  (reused as FFN hidden)
    float* t    = feat + 16777216;      // 8192*384         =  3,145,728
    float* q    = t + 3145728;
    float* kbuf = q + 3145728;          // also reused as pre-LN y buffer
    float* vbuf = kbuf + 3145728;
    // total = 29,409,280 floats ≈ 118 MB

    const int ROWS = 8192;

    pe_kernel<<<128, 384, 0, stream>>>(pe);
    cnn_kernel<<<8192, 256, 0, stream>>>(x, cw0, cb0, cw1, cb1, cw2, cb2, feat);
    // t = relu(feat @ embed_w + embed_b) + pe
    gemm_f32<5><<<dim3(6, 128), 256, 0, stream>>>(feat, ew, eb, nullptr, pe, t,
                                                  ROWS, 384, 2048);
    for (int i = 0; i < 4; ++i) {
        const float* Wqi = Wq + (size_t)i * 147456;
        const float* Wki = Wk + (size_t)i * 147456;
        const float* Wvi = Wv + (size_t)i * 147456;
        const float* Woi = Wo + (size_t)i * 147456;
        const float* W1i = W1 + (size_t)i * 589824;
        const float* W2i = W2 + (size_t)i * 589824;
        gemm_f32<0><<<dim3(6, 128), 256, 0, stream>>>(t, Wqi, bq + i * 384, nullptr,
                                                      nullptr, q, ROWS, 384, 384);
        gemm_f32<0><<<dim3(6, 128), 256, 0, stream>>>(t, Wki, bk + i * 384, nullptr,
                                                      nullptr, kbuf, ROWS, 384, 384);
        gemm_f32<0><<<dim3(6, 128), 256, 0, stream>>>(t, Wvi, bv + i * 384, nullptr,
                                                      nullptr, vbuf, ROWS, 384, 384);
        attn_kernel<<<512, 128, 0, stream>>>(q, kbuf, vbuf, q);  // o -> q (in place)
        // y = o @ Wo + bo + t   -> kbuf
        gemm_f32<2><<<dim3(6, 128), 256, 0, stream>>>(q, Woi, bo + i * 384, t,
                                                      nullptr, kbuf, ROWS, 384, 384);
        ln_kernel<<<2048, 256, 0, stream>>>(kbuf, g1 + i * 384, be1 + i * 384, t);
        // ffn hidden = relu(t @ W1 + b1) -> feat
        gemm_f32<1><<<dim3(24, 128), 256, 0, stream>>>(t, W1i, b1 + i * 1536, nullptr,
                                                       nullptr, feat, ROWS, 1536, 384);
        // y = hidden @ W2 + b2 + t -> kbuf
        gemm_f32<2><<<dim3(6, 128), 256, 0, stream>>>(feat, W2i, b2 + i * 384, t,
                                                      nullptr, kbuf, ROWS, 384, 1536);
        ln_kernel<<<2048, 256, 0, stream>>>(kbuf, g2 + i * 384, be2 + i * 384, t);
    }
    head_kernel<<<64, 384, 0, stream>>>(t, clw, clb, (float*)d_out);
}

// Round 2
// 1160.030 us; speedup vs baseline: 2.1994x; 2.1994x over previous
//
#include <hip/hip_runtime.h>
#include <math.h>

// ---------------------------------------------------------------------------
// N=64, L=128, W=256, D=384, H=8, E=48, NL=4, DFF=1536, rows = N*L = 8192
// All GEMMs: bf16 MFMA (16x16x32), A [M][K] bf16 row-major, Bt [N][K] bf16.
// ---------------------------------------------------------------------------

typedef float f32x4 __attribute__((ext_vector_type(4)));
typedef short bf16x8 __attribute__((ext_vector_type(8)));

__device__ __forceinline__ short f2bf(float f) {
    union { float f; unsigned u; } c; c.f = f;
    unsigned r = (c.u + 0x7FFFu + ((c.u >> 16) & 1u)) >> 16;
    return (short)r;
}
__device__ __forceinline__ float bf2f(short s) {
    union { unsigned u; float f; } c;
    c.u = ((unsigned)(unsigned short)s) << 16;
    return c.f;
}

__device__ __forceinline__ void gload_lds16(const void* g, void* l) {
    __builtin_amdgcn_global_load_lds(
        (const __attribute__((address_space(1))) unsigned int*)g,
        (__attribute__((address_space(3))) unsigned int*)l,
        16, 0, 0);
}

// ---------------- positional encoding table: pe[l][d], l<128, d<384 --------
__global__ __launch_bounds__(384) void pe_kernel(float* __restrict__ pe) {
    int l = blockIdx.x, d = threadIdx.x;
    int i2 = d >> 1;
    float ang = (float)l * expf(-(2.0f * (float)i2 / 384.0f) * 9.210340371976184f);
    pe[l * 384 + d] = (d & 1) ? cosf(ang) : sinf(ang);
}

// ---------------- weight convert+transpose: W fp32 [K][N] -> Wt bf16 [N][K] -
__global__ __launch_bounds__(256) void wcvt_kernel(
    const float* __restrict__ W, short* __restrict__ Wt, int K, int N)
{
    __shared__ float tile[32][33];
    int kb = blockIdx.x * 32, nb = blockIdx.y * 32;
    size_t off = (size_t)blockIdx.z * K * N;
    const float* Wp = W + off;
    short* Wtp = Wt + off;
    int tx = threadIdx.x & 31, ty = threadIdx.x >> 5;
    #pragma unroll
    for (int r = ty; r < 32; r += 8)
        tile[r][tx] = Wp[(size_t)(kb + r) * N + nb + tx];
    __syncthreads();
    #pragma unroll
    for (int r = ty; r < 32; r += 8)
        Wtp[(size_t)(nb + r) * K + kb + tx] = f2bf(tile[tx][r]);
}

// ---------------- fused CNN window encoder (outputs bf16 feat) -------------
__global__ __launch_bounds__(256) void cnn_kernel(
    const float* __restrict__ x,
    const float* __restrict__ w0, const float* __restrict__ b0,
    const float* __restrict__ w1, const float* __restrict__ b1,
    const float* __restrict__ w2, const float* __restrict__ b2,
    short* __restrict__ feat)
{
    __shared__ float xs[256];
    __shared__ float a0[4][256];
    __shared__ float p0[4][129];
    __shared__ float a1[16][129];
    __shared__ float p1[16][65];
    __shared__ float a2[64][65];
    __shared__ float w2s[16][7][64];
    __shared__ float w1s[64][7];
    __shared__ float w0s[4][7];

    int tid = threadIdx.x;
    int win = blockIdx.x;

    xs[tid] = x[(size_t)win * 256 + tid];
    if (tid < 28) ((float*)w0s)[tid] = w0[tid];
    if (tid < 64) {
        for (int k = 0; k < 7; ++k) w1s[tid][k] = w1[tid * 7 + k];
    }
    for (int idx = tid; idx < 7168; idx += 256) {
        int c = idx / 112;
        int r = idx - c * 112;
        int ci = r / 7;
        int k = r - ci * 7;
        w2s[ci][k][c] = w2[idx];
    }
    __syncthreads();

    #pragma unroll
    for (int r = 0; r < 4; ++r) {
        int c = r, i = tid;
        float acc = b0[c];
        #pragma unroll
        for (int k = 0; k < 7; ++k) {
            int j = i + k - 3;
            float v = (j >= 0 && j < 256) ? xs[j] : 0.f;
            acc = fmaf(w0s[c][k], v, acc);
        }
        a0[c][i] = fmaxf(acc, 0.f);
    }
    __syncthreads();
    #pragma unroll
    for (int r = 0; r < 2; ++r) {
        int idx = tid + 256 * r;
        int c = idx >> 7, j = idx & 127;
        p0[c][j] = fmaxf(a0[c][2 * j], a0[c][2 * j + 1]);
    }
    __syncthreads();
    {
        int c = tid >> 4;
        int i0 = (tid & 15) * 8;
        float acc[8];
        float bb = b1[c];
        #pragma unroll
        for (int m = 0; m < 8; ++m) acc[m] = bb;
        #pragma unroll
        for (int ci = 0; ci < 4; ++ci) {
            float rv[14];
            #pragma unroll
            for (int u = 0; u < 14; ++u) {
                int j = i0 + u - 3;
                rv[u] = (j >= 0 && j < 128) ? p0[ci][j] : 0.f;
            }
            #pragma unroll
            for (int k = 0; k < 7; ++k) {
                float w = w1s[c * 4 + ci][k];
                #pragma unroll
                for (int m = 0; m < 8; ++m) acc[m] = fmaf(w, rv[m + k], acc[m]);
            }
        }
        #pragma unroll
        for (int m = 0; m < 8; ++m) a1[c][i0 + m] = fmaxf(acc[m], 0.f);
    }
    __syncthreads();
    #pragma unroll
    for (int r = 0; r < 4; ++r) {
        int idx = tid + 256 * r;
        int c = idx >> 6, j = idx & 63;
        p1[c][j] = fmaxf(a1[c][2 * j], a1[c][2 * j + 1]);
    }
    __syncthreads();
    {
        int c = tid >> 2;
        int i0 = (tid & 3) * 16;
        float acc[16];
        float bb = b2[c];
        #pragma unroll
        for (int m = 0; m < 16; ++m) acc[m] = bb;
        for (int ci = 0; ci < 16; ++ci) {
            float rv[22];
            #pragma unroll
            for (int u = 0; u < 22; ++u) {
                int j = i0 + u - 3;
                rv[u] = (j >= 0 && j < 64) ? p1[ci][j] : 0.f;
            }
            #pragma unroll
            for (int k = 0; k < 7; ++k) {
                float w = w2s[ci][k][c];
                #pragma unroll
                for (int m = 0; m < 16; ++m) acc[m] = fmaf(w, rv[m + k], acc[m]);
            }
        }
        #pragma unroll
        for (int m = 0; m < 16; ++m) a2[c][i0 + m] = fmaxf(acc[m], 0.f);
    }
    __syncthreads();
    #pragma unroll
    for (int r = 0; r < 8; ++r) {
        int idx = tid + 256 * r;
        int c = idx >> 5, j = idx & 31;
        feat[(size_t)win * 2048 + idx] = f2bf(fmaxf(a2[c][2 * j], a2[c][2 * j + 1]));
    }
}

// ---------------- bf16 MFMA GEMM: C = A[M][K] * Bt[N][K]^T -----------------
// Tile: BM=64, BN=64, BK=64. 128 threads = 2 waves; wave w covers cols
// w*32..w*32+31, rows 0..63 (acc[4][2] of 16x16x32 frags).
// LDS layout: row-major [rows][64] bf16 (128B/row = 8 slots of 16B),
// slot XOR-swizzled by (row&7). Swizzle applied by permuting the gather.
// EPI bits: 1=relu, 2=+resid(f32), 4=+pe, 8=write f32, 16=write bf16
template <int EPI>
__global__ __launch_bounds__(128) void gemm_bf16(
    const short* __restrict__ A, const short* __restrict__ Bt,
    const float* __restrict__ bias, const float* __restrict__ resid,
    const float* __restrict__ pe, float* __restrict__ outF,
    short* __restrict__ outB, int M, int N, int K)
{
    __shared__ short As[64 * 64];
    __shared__ short Bs[64 * 64];
    int tid = threadIdx.x;
    int w = tid >> 6, lane = tid & 63;
    int m0 = blockIdx.y * 64, n0 = blockIdx.x * 64;

    // staging: lane -> (row_local = lane>>3, slot = lane&7); 4 loads each side
    int rl = lane >> 3, sl = lane & 7;
    const short* aptr[4];
    const short* bptr[4];
    #pragma unroll
    for (int l = 0; l < 4; ++l) {
        int r = w * 32 + l * 8 + rl;
        int cb = sl ^ (r & 7);
        aptr[l] = A + (size_t)(m0 + r) * K + cb * 8;
        bptr[l] = Bt + (size_t)(n0 + r) * K + cb * 8;
    }

    int cq = lane >> 4, cl = lane & 15;
    f32x4 acc[4][2];
    #pragma unroll
    for (int mt = 0; mt < 4; ++mt)
        #pragma unroll
        for (int nt = 0; nt < 2; ++nt)
            acc[mt][nt] = (f32x4){0.f, 0.f, 0.f, 0.f};

    for (int k0 = 0; k0 < K; k0 += 64) {
        #pragma unroll
        for (int l = 0; l < 4; ++l) {
            gload_lds16(aptr[l], &As[(w * 32 + l * 8) * 64]);
            gload_lds16(bptr[l], &Bs[(w * 32 + l * 8) * 64]);
            aptr[l] += 64;
            bptr[l] += 64;
        }
        __syncthreads();
        #pragma unroll
        for (int s = 0; s < 2; ++s) {
            bf16x8 af[4], bfr[2];
            #pragma unroll
            for (int mt = 0; mt < 4; ++mt) {
                int r = mt * 16 + cl;
                int slot = (s * 4 + cq) ^ (r & 7);
                af[mt] = *(const bf16x8*)&As[r * 64 + slot * 8];
            }
            #pragma unroll
            for (int nt = 0; nt < 2; ++nt) {
                int r = w * 32 + nt * 16 + cl;
                int slot = (s * 4 + cq) ^ (r & 7);
                bfr[nt] = *(const bf16x8*)&Bs[r * 64 + slot * 8];
            }
            #pragma unroll
            for (int mt = 0; mt < 4; ++mt)
                #pragma unroll
                for (int nt = 0; nt < 2; ++nt)
                    acc[mt][nt] = __builtin_amdgcn_mfma_f32_16x16x32_bf16(
                        af[mt], bfr[nt], acc[mt][nt], 0, 0, 0);
        }
        __syncthreads();
    }

    #pragma unroll
    for (int mt = 0; mt < 4; ++mt) {
        #pragma unroll
        for (int nt = 0; nt < 2; ++nt) {
            int col = n0 + w * 32 + nt * 16 + cl;
            float bb = bias[col];
            #pragma unroll
            for (int rg = 0; rg < 4; ++rg) {
                int row = m0 + mt * 16 + cq * 4 + rg;
                float v = acc[mt][nt][rg] + bb;
                if (EPI & 1) v = fmaxf(v, 0.f);
                if (EPI & 4) v += pe[(row & 127) * 384 + col];
                if (EPI & 2) v += resid[(size_t)row * N + col];
                if (EPI & 8) outF[(size_t)row * N + col] = v;
                if (EPI & 16) outB[(size_t)row * N + col] = f2bf(v);
            }
        }
    }
}

// ---------------- fused attention per (n,h): online softmax, bf16 io -------
// o aliases q (block reads its own q slice into regs before any writes,
// slices across blocks are disjoint)
__global__ __launch_bounds__(128) void attn_kernel(
    const short* q, const short* __restrict__ k,
    const short* __restrict__ v, short* o)
{
    __shared__ float Ks[128][48];
    __shared__ float Vs[128][48];
    int tid = threadIdx.x;
    int n = blockIdx.x >> 3, h = blockIdx.x & 7;
    size_t base = (size_t)n * 128 * 384 + (size_t)h * 48;
    for (int idx = tid; idx < 6144; idx += 128) {
        int s = idx / 48, e = idx - s * 48;
        Ks[s][e] = bf2f(k[base + (size_t)s * 384 + e]);
        Vs[s][e] = bf2f(v[base + (size_t)s * 384 + e]);
    }
    float qr[48];
    const short* qp = q + base + (size_t)tid * 384;
    #pragma unroll
    for (int e = 0; e < 48; ++e) qr[e] = bf2f(qp[e]);
    __syncthreads();

    float m = -1e30f, denom = 0.f;
    float acc[48];
    #pragma unroll
    for (int e = 0; e < 48; ++e) acc[e] = 0.f;
    const float temp = 0.14433756729740643f;  // 1/sqrt(48)
    for (int s = 0; s < 128; ++s) {
        float sc = 0.f;
        #pragma unroll
        for (int e = 0; e < 48; ++e) sc = fmaf(qr[e], Ks[s][e], sc);
        sc *= temp;
        float nm = fmaxf(m, sc);
        float alpha = __expf(m - nm);
        float p = __expf(sc - nm);
        denom = denom * alpha + p;
        #pragma unroll
        for (int e = 0; e < 48; ++e) acc[e] = fmaf(p, Vs[s][e], acc[e] * alpha);
        m = nm;
    }
    float inv = 1.f / denom;
    short* op = o + base + (size_t)tid * 384;
    #pragma unroll
    for (int e = 0; e < 48; ++e) op[e] = f2bf(acc[e] * inv);
}

// ---------------- LayerNorm (wave per row, D=384), dual output -------------
__global__ __launch_bounds__(256) void ln_kernel(
    const float* __restrict__ y, const float* __restrict__ g,
    const float* __restrict__ b, float* __restrict__ t, short* __restrict__ tb)
{
    int row = blockIdx.x * 4 + (threadIdx.x >> 6);
    int lane = threadIdx.x & 63;
    const float* yr = y + (size_t)row * 384;
    float vals[6];
    float s = 0.f, s2 = 0.f;
    #pragma unroll
    for (int mi = 0; mi < 6; ++mi) {
        float vv = yr[lane + mi * 64];
        vals[mi] = vv;
        s += vv;
        s2 = fmaf(vv, vv, s2);
    }
    #pragma unroll
    for (int off = 32; off > 0; off >>= 1) {
        s += __shfl_xor(s, off, 64);
        s2 += __shfl_xor(s2, off, 64);
    }
    float mean = s * (1.f / 384.f);
    float var = s2 * (1.f / 384.f) - mean * mean;
    float inv = rsqrtf(var + 1e-5f);
    float* tr = t + (size_t)row * 384;
    short* tbr = tb + (size_t)row * 384;
    #pragma unroll
    for (int mi = 0; mi < 6; ++mi) {
        int d = lane + mi * 64;
        float vv = (vals[mi] - mean) * inv * g[d] + b[d];
        tr[d] = vv;
        tbr[d] = f2bf(vv);
    }
}

// ---------------- classifier head ------------------------------------------
__global__ __launch_bounds__(384) void head_kernel(
    const float* __restrict__ t, const float* __restrict__ cls_w,
    const float* __restrict__ cls_b, float* __restrict__ out)
{
    int n = blockIdx.x, d = threadIdx.x;
    float s = 0.f;
    for (int l = 0; l < 128; ++l) s += t[((size_t)n * 128 + l) * 384 + d];
    float p = s * (1.f / 128.f) * cls_w[d];
    #pragma unroll
    for (int off = 32; off > 0; off >>= 1) p += __shfl_xor(p, off, 64);
    __shared__ float red[6];
    if ((threadIdx.x & 63) == 0) red[threadIdx.x >> 6] = p;
    __syncthreads();
    if (threadIdx.x == 0) {
        float tot = red[0] + red[1] + red[2] + red[3] + red[4] + red[5];
        out[n] = tot + cls_b[0];
    }
}

// ---------------------------------------------------------------------------
extern "C" void kernel_launch(void* const* d_in, const int* in_sizes, int n_in,
                              void* d_out, int out_size, void* d_ws, size_t ws_size,
                              hipStream_t stream) {
    (void)n_in; (void)out_size; (void)ws_size;
    const float* x   = (const float*)d_in[0];
    const float* cw0 = (const float*)d_in[1];
    const float* cb0 = (const float*)d_in[2];
    const float* cw1 = (const float*)d_in[3];
    const float* cb1 = (const float*)d_in[4];
    const float* cw2 = (const float*)d_in[5];
    const float* cb2 = (const float*)d_in[6];
    const float* ew  = (const float*)d_in[7];
    const float* eb  = (const float*)d_in[8];
    bool dict_order = (in_sizes[10] == 589824);
    const float *Wq, *Wk, *Wv, *Wo, *W1, *W2, *bq, *bk, *bv, *bo, *b1, *b2;
    if (dict_order) {
        Wq = (const float*)d_in[9];  Wk = (const float*)d_in[10];
        Wv = (const float*)d_in[11]; Wo = (const float*)d_in[12];
        W1 = (const float*)d_in[13]; W2 = (const float*)d_in[14];
        bq = (const float*)d_in[15]; bk = (const float*)d_in[16];
        bv = (const float*)d_in[17]; bo = (const float*)d_in[18];
        b1 = (const float*)d_in[19]; b2 = (const float*)d_in[20];
    } else {
        Wq = (const float*)d_in[9];  bq = (const float*)d_in[10];
        Wk = (const float*)d_in[11]; bk = (const float*)d_in[12];
        Wv = (const float*)d_in[13]; bv = (const float*)d_in[14];
        Wo = (const float*)d_in[15]; bo = (const float*)d_in[16];
        W1 = (const float*)d_in[17]; b1 = (const float*)d_in[18];
        W2 = (const float*)d_in[19]; b2 = (const float*)d_in[20];
    }
    const float* g1  = (const float*)d_in[21];
    const float* be1 = (const float*)d_in[22];
    const float* g2  = (const float*)d_in[23];
    const float* be2 = (const float*)d_in[24];
    const float* clw = (const float*)d_in[25];
    const float* clb = (const float*)d_in[26];

    // ---- workspace layout (bytes) ----
    char* wp = (char*)d_ws;
    float* pe    = (float*)wp; wp += 196608;       // 128*384 f32
    short* featb = (short*)wp; wp += 33554432;     // 8192*2048 bf16 (reused as FFN hidden)
    float* t     = (float*)wp; wp += 12582912;     // 8192*384 f32
    short* tb    = (short*)wp; wp += 6291456;      // 8192*384 bf16
    short* qb    = (short*)wp; wp += 6291456;
    short* kb    = (short*)wp; wp += 6291456;
    short* vb    = (short*)wp; wp += 6291456;
    float* y     = (float*)wp; wp += 12582912;     // pre-LN f32
    short* ewT   = (short*)wp; wp += 1572864;      // 384 x 2048
    short* WqT   = (short*)wp; wp += 4718592;      // 4 x 384 x 384
    short* WkT   = (short*)wp; wp += 4718592;
    short* WvT   = (short*)wp; wp += 4718592;
    short* WoT   = (short*)wp; wp += 4718592;
    short* W1T   = (short*)wp; wp += 4718592;      // 4 x 1536 x 384 (as [N][K])
    short* W2T   = (short*)wp; wp += 4718592;      // 4 x 384 x 1536
    short* hb    = featb;                          // FFN hidden 8192*1536 bf16

    const int ROWS = 8192;

    pe_kernel<<<128, 384, 0, stream>>>(pe);
    wcvt_kernel<<<dim3(64, 12, 1), 256, 0, stream>>>(ew, ewT, 2048, 384);
    wcvt_kernel<<<dim3(12, 12, 4), 256, 0, stream>>>(Wq, WqT, 384, 384);
    wcvt_kernel<<<dim3(12, 12, 4), 256, 0, stream>>>(Wk, WkT, 384, 384);
    wcvt_kernel<<<dim3(12, 12, 4), 256, 0, stream>>>(Wv, WvT, 384, 384);
    wcvt_kernel<<<dim3(12, 12, 4), 256, 0, stream>>>(Wo, WoT, 384, 384);
    wcvt_kernel<<<dim3(12, 48, 4), 256, 0, stream>>>(W1, W1T, 384, 1536);
    wcvt_kernel<<<dim3(48, 12, 4), 256, 0, stream>>>(W2, W2T, 1536, 384);
    cnn_kernel<<<8192, 256, 0, stream>>>(x, cw0, cb0, cw1, cb1, cw2, cb2, featb);

    // t/tb = relu(feat @ ew + eb) + pe
    gemm_bf16<29><<<dim3(6, 128), 128, 0, stream>>>(featb, ewT, eb, nullptr, pe,
                                                    t, tb, ROWS, 384, 2048);
    for (int i = 0; i < 4; ++i) {
        const short* WqTi = WqT + (size_t)i * 147456;
        const short* WkTi = WkT + (size_t)i * 147456;
        const short* WvTi = WvT + (size_t)i * 147456;
        const short* WoTi = WoT + (size_t)i * 147456;
        const short* W1Ti = W1T + (size_t)i * 589824;
        const short* W2Ti = W2T + (size_t)i * 589824;
        gemm_bf16<16><<<dim3(6, 128), 128, 0, stream>>>(tb, WqTi, bq + i * 384,
            nullptr, nullptr, nullptr, qb, ROWS, 384, 384);
        gemm_bf16<16><<<dim3(6, 128), 128, 0, stream>>>(tb, WkTi, bk + i * 384,
            nullptr, nullptr, nullptr, kb, ROWS, 384, 384);
        gemm_bf16<16><<<dim3(6, 128), 128, 0, stream>>>(tb, WvTi, bv + i * 384,
            nullptr, nullptr, nullptr, vb, ROWS, 384, 384);
        attn_kernel<<<512, 128, 0, stream>>>(qb, kb, vb, qb);  // o -> qb in place
        // y = o @ Wo + bo + t
        gemm_bf16<10><<<dim3(6, 128), 128, 0, stream>>>(qb, WoTi, bo + i * 384,
            t, nullptr, y, nullptr, ROWS, 384, 384);
        ln_kernel<<<2048, 256, 0, stream>>>(y, g1 + i * 384, be1 + i * 384, t, tb);
        // hidden = relu(t @ W1 + b1)
        gemm_bf16<17><<<dim3(24, 128), 128, 0, stream>>>(tb, W1Ti, b1 + i * 1536,
            nullptr, nullptr, nullptr, hb, ROWS, 1536, 384);
        // y = hidden @ W2 + b2 + t
        gemm_bf16<10><<<dim3(6, 128), 128, 0, stream>>>(hb, W2Ti, b2 + i * 384,
            t, nullptr, y, nullptr, ROWS, 384, 1536);
        ln_kernel<<<2048, 256, 0, stream>>>(y, g2 + i * 384, be2 + i * 384, t, tb);
    }
    head_kernel<<<64, 384, 0, stream>>>(t, clw, clb, (float*)d_out);
}

// Round 3
// 1034.968 us; speedup vs baseline: 2.4652x; 1.1208x over previous
//
#include <hip/hip_runtime.h>
#include <math.h>

// ---------------------------------------------------------------------------
// N=64, L=128, W=256, D=384, H=8, E=48, NL=4, DFF=1536, rows = N*L = 8192
// GEMMs: bf16 MFMA 16x16x32, A [M][K] bf16 row-major, Bt [N][K] bf16.
// ---------------------------------------------------------------------------

typedef float f32x4 __attribute__((ext_vector_type(4)));
typedef short bf16x8 __attribute__((ext_vector_type(8)));
typedef short s16x4 __attribute__((ext_vector_type(4)));

__device__ __forceinline__ short f2bf(float f) {
    union { float f; unsigned u; } c; c.f = f;
    unsigned r = (c.u + 0x7FFFu + ((c.u >> 16) & 1u)) >> 16;
    return (short)r;
}
__device__ __forceinline__ float bf2f(short s) {
    union { unsigned u; float f; } c;
    c.u = ((unsigned)(unsigned short)s) << 16;
    return c.f;
}

__device__ __forceinline__ void gload_lds16(const void* g, void* l) {
    __builtin_amdgcn_global_load_lds(
        (const __attribute__((address_space(1))) unsigned int*)g,
        (__attribute__((address_space(3))) unsigned int*)l,
        16, 0, 0);
}

// ---------------- positional encoding table: pe[l][d] ----------------------
__global__ __launch_bounds__(384) void pe_kernel(float* __restrict__ pe) {
    int l = blockIdx.x, d = threadIdx.x;
    int i2 = d >> 1;
    float ang = (float)l * expf(-(2.0f * (float)i2 / 384.0f) * 9.210340371976184f);
    pe[l * 384 + d] = (d & 1) ? cosf(ang) : sinf(ang);
}

// ---------------- weight convert+transpose: W fp32 [K][N] -> bf16 [N][K] ---
// block z: src = W + z*srcZ ; dst = Wt + z*dstZ + dstOff
__global__ __launch_bounds__(256) void wcvt_kernel(
    const float* __restrict__ W, short* __restrict__ Wt, int K, int N,
    int dstOff, int srcZ, int dstZ)
{
    __shared__ float tile[32][33];
    int kb = blockIdx.x * 32, nb = blockIdx.y * 32;
    const float* Wp = W + (size_t)blockIdx.z * srcZ;
    short* Wtp = Wt + (size_t)blockIdx.z * dstZ + dstOff;
    int tx = threadIdx.x & 31, ty = threadIdx.x >> 5;
    #pragma unroll
    for (int r = ty; r < 32; r += 8)
        tile[r][tx] = Wp[(size_t)(kb + r) * N + nb + tx];
    __syncthreads();
    #pragma unroll
    for (int r = ty; r < 32; r += 8)
        Wtp[(size_t)(nb + r) * K + kb + tx] = f2bf(tile[tx][r]);
}

// ---------------- concatenated qkv bias: bqkv[l][1152] ---------------------
__global__ __launch_bounds__(384) void biascat_kernel(
    const float* __restrict__ bq, const float* __restrict__ bk,
    const float* __restrict__ bv, float* __restrict__ bqkv)
{
    int l = blockIdx.x, j = threadIdx.x;
    bqkv[l * 1152 + j] = bq[l * 384 + j];
    bqkv[l * 1152 + 384 + j] = bk[l * 384 + j];
    bqkv[l * 1152 + 768 + j] = bv[l * 384 + j];
}

// ---------------- fused CNN window encoder (bf16 out) ----------------------
// One block per window. Each conv+relu+pool stage fused (pool pairs stay
// within one thread's output run). Thread maps chosen so each wave reads
// only a few distinct LDS addresses per instruction (broadcast, no 4-way
// conflicts): stage B uses c=tid&15 (channel fastest), i0=(tid>>4)*8.
__global__ __launch_bounds__(256) void cnn_kernel(
    const float* __restrict__ x,
    const float* __restrict__ w0, const float* __restrict__ b0,
    const float* __restrict__ w1, const float* __restrict__ b1,
    const float* __restrict__ w2, const float* __restrict__ b2,
    short* __restrict__ feat)
{
    __shared__ float xs[256];
    __shared__ float p0[4][129];
    __shared__ float p1[16][65];
    __shared__ float w2s[16][7][64];   // [ci][k][c]
    __shared__ float w1s[64][7];       // [(c*4+ci)][k]
    __shared__ float w0s[4][7];

    int tid = threadIdx.x;
    int win = blockIdx.x;

    xs[tid] = x[(size_t)win * 256 + tid];
    if (tid < 28) ((float*)w0s)[tid] = w0[tid];
    if (tid < 64) {
        for (int k = 0; k < 7; ++k) w1s[tid][k] = w1[tid * 7 + k];
    }
    for (int idx = tid; idx < 7168; idx += 256) {
        int c = idx / 112;
        int r = idx - c * 112;
        int ci = r / 7;
        int k = r - ci * 7;
        w2s[ci][k][c] = w2[idx];
    }
    __syncthreads();

    // ---- stage A: conv0 (1->4) + relu + pool2 -> p0[4][128] ----
    {
        int c = tid & 3, p = tid >> 2;      // p in 0..63
        float bb = b0[c];
        #pragma unroll
        for (int t2 = 0; t2 < 2; ++t2) {
            int pp = p + 64 * t2;           // pooled position 0..127
            float rv[9];
            #pragma unroll
            for (int u = 0; u < 9; ++u) {
                int j = 2 * pp + u - 3;
                rv[u] = (j >= 0 && j < 256) ? xs[j] : 0.f;
            }
            float a0 = bb, a1 = bb;
            #pragma unroll
            for (int k = 0; k < 7; ++k) {
                float w = w0s[c][k];
                a0 = fmaf(w, rv[k], a0);
                a1 = fmaf(w, rv[k + 1], a1);
            }
            p0[c][pp] = fmaxf(fmaxf(a0, a1), 0.f);
        }
    }
    __syncthreads();

    // ---- stage B: conv1 (4->16) + relu + pool2 -> p1[16][64] ----
    {
        int c = tid & 15;
        int i0 = (tid >> 4) * 8;            // conv positions i0..i0+7
        float acc[8];
        float bb = b1[c];
        #pragma unroll
        for (int m = 0; m < 8; ++m) acc[m] = bb;
        #pragma unroll
        for (int ci = 0; ci < 4; ++ci) {
            float rv[14];
            #pragma unroll
            for (int u = 0; u < 14; ++u) {
                int j = i0 + u - 3;
                rv[u] = (j >= 0 && j < 128) ? p0[ci][j] : 0.f;
            }
            #pragma unroll
            for (int k = 0; k < 7; ++k) {
                float w = w1s[c * 4 + ci][k];
                #pragma unroll
                for (int m = 0; m < 8; ++m) acc[m] = fmaf(w, rv[m + k], acc[m]);
            }
        }
        int po = i0 >> 1;                   // pooled positions po..po+3
        #pragma unroll
        for (int m = 0; m < 4; ++m)
            p1[c][po + m] = fmaxf(fmaxf(acc[2 * m], acc[2 * m + 1]), 0.f);
    }
    __syncthreads();

    // ---- stage C: conv2 (16->64) + relu + pool2 -> feat (bf16) ----
    {
        int c = tid & 63;                   // out channel; uniform pi per wave
        int i0 = (tid >> 6) * 16;           // conv positions i0..i0+15
        float acc[16];
        float bb = b2[c];
        #pragma unroll
        for (int m = 0; m < 16; ++m) acc[m] = bb;
        for (int ci = 0; ci < 16; ++ci) {
            float rv[22];
            #pragma unroll
            for (int u = 0; u < 22; ++u) {
                int j = i0 + u - 3;
                rv[u] = (j >= 0 && j < 64) ? p1[ci][j] : 0.f;
            }
            #pragma unroll
            for (int k = 0; k < 7; ++k) {
                float w = w2s[ci][k][c];
                #pragma unroll
                for (int m = 0; m < 16; ++m) acc[m] = fmaf(w, rv[m + k], acc[m]);
            }
        }
        int po = i0 >> 1;                   // pooled 8 outputs
        short* fp = feat + (size_t)win * 2048 + c * 32 + po;
        #pragma unroll
        for (int m = 0; m < 8; ++m)
            fp[m] = f2bf(fmaxf(fmaxf(acc[2 * m], acc[2 * m + 1]), 0.f));
    }
}

// ---------------- bf16 MFMA GEMM: C = A[M][K] * Bt[N][K]^T -----------------
// BM=64, BN=64, BK=64; 128 threads = 2 waves; wave w: cols w*32..+31,
// rows 0..63 (4x2 frags of 16x16x32). XOR-swizzled LDS (slot ^= row&7).
// EPI bits: 1=relu, 2=+resid(f32), 4=+pe, 8=write f32, 16=write bf16
template <int EPI>
__global__ __launch_bounds__(128) void gemm_bf16(
    const short* __restrict__ A, const short* __restrict__ Bt,
    const float* __restrict__ bias, const float* __restrict__ resid,
    const float* __restrict__ pe, float* __restrict__ outF,
    short* __restrict__ outB, int M, int N, int K)
{
    __shared__ short As[64 * 64];
    __shared__ short Bs[64 * 64];
    int tid = threadIdx.x;
    int w = tid >> 6, lane = tid & 63;
    int m0 = blockIdx.y * 64, n0 = blockIdx.x * 64;

    int rl = lane >> 3, sl = lane & 7;
    const short* aptr[4];
    const short* bptr[4];
    #pragma unroll
    for (int l = 0; l < 4; ++l) {
        int r = w * 32 + l * 8 + rl;
        int cb = sl ^ (r & 7);
        aptr[l] = A + (size_t)(m0 + r) * K + cb * 8;
        bptr[l] = Bt + (size_t)(n0 + r) * K + cb * 8;
    }

    int cq = lane >> 4, cl = lane & 15;
    f32x4 acc[4][2];
    #pragma unroll
    for (int mt = 0; mt < 4; ++mt)
        #pragma unroll
        for (int nt = 0; nt < 2; ++nt)
            acc[mt][nt] = (f32x4){0.f, 0.f, 0.f, 0.f};

    for (int k0 = 0; k0 < K; k0 += 64) {
        #pragma unroll
        for (int l = 0; l < 4; ++l) {
            gload_lds16(aptr[l], &As[(w * 32 + l * 8) * 64]);
            gload_lds16(bptr[l], &Bs[(w * 32 + l * 8) * 64]);
            aptr[l] += 64;
            bptr[l] += 64;
        }
        __syncthreads();
        #pragma unroll
        for (int s = 0; s < 2; ++s) {
            bf16x8 af[4], bfr[2];
            #pragma unroll
            for (int mt = 0; mt < 4; ++mt) {
                int r = mt * 16 + cl;
                int slot = (s * 4 + cq) ^ (r & 7);
                af[mt] = *(const bf16x8*)&As[r * 64 + slot * 8];
            }
            #pragma unroll
            for (int nt = 0; nt < 2; ++nt) {
                int r = w * 32 + nt * 16 + cl;
                int slot = (s * 4 + cq) ^ (r & 7);
                bfr[nt] = *(const bf16x8*)&Bs[r * 64 + slot * 8];
            }
            #pragma unroll
            for (int mt = 0; mt < 4; ++mt)
                #pragma unroll
                for (int nt = 0; nt < 2; ++nt)
                    acc[mt][nt] = __builtin_amdgcn_mfma_f32_16x16x32_bf16(
                        af[mt], bfr[nt], acc[mt][nt], 0, 0, 0);
        }
        __syncthreads();
    }

    #pragma unroll
    for (int mt = 0; mt < 4; ++mt) {
        #pragma unroll
        for (int nt = 0; nt < 2; ++nt) {
            int col = n0 + w * 32 + nt * 16 + cl;
            float bb = bias[col];
            #pragma unroll
            for (int rg = 0; rg < 4; ++rg) {
                int row = m0 + mt * 16 + cq * 4 + rg;
                float v = acc[mt][nt][rg] + bb;
                if (EPI & 1) v = fmaxf(v, 0.f);
                if (EPI & 4) v += pe[(row & 127) * 384 + col];
                if (EPI & 2) v += resid[(size_t)row * N + col];
                if (EPI & 8) outF[(size_t)row * N + col] = v;
                if (EPI & 16) outB[(size_t)row * N + col] = f2bf(v);
            }
        }
    }
}

// ---------------- fused attention per (n,h), qkv packed [rows][1152] -------
__global__ __launch_bounds__(128) void attn_kernel(
    const short* __restrict__ qkv, short* __restrict__ o)
{
    __shared__ float Ks[128][48];
    __shared__ float Vs[128][48];
    int tid = threadIdx.x;
    int n = blockIdx.x >> 3, h = blockIdx.x & 7;
    size_t base = (size_t)n * 128 * 1152 + (size_t)h * 48;
    const short* kp = qkv + base + 384;
    const short* vp = qkv + base + 768;
    for (int i = tid; i < 1536; i += 128) {
        int s = i / 12, e4 = (i - s * 12) * 4;
        s16x4 kv = *(const s16x4*)(kp + (size_t)s * 1152 + e4);
        s16x4 vv = *(const s16x4*)(vp + (size_t)s * 1152 + e4);
        #pragma unroll
        for (int j = 0; j < 4; ++j) {
            Ks[s][e4 + j] = bf2f(kv[j]);
            Vs[s][e4 + j] = bf2f(vv[j]);
        }
    }
    float qr[48];
    {
        const short* qp = qkv + base + (size_t)tid * 1152;
        #pragma unroll
        for (int e4 = 0; e4 < 12; ++e4) {
            s16x4 qv = *(const s16x4*)(qp + e4 * 4);
            #pragma unroll
            for (int j = 0; j < 4; ++j) qr[e4 * 4 + j] = bf2f(qv[j]);
        }
    }
    __syncthreads();

    float m = -1e30f, denom = 0.f;
    float acc[48];
    #pragma unroll
    for (int e = 0; e < 48; ++e) acc[e] = 0.f;
    const float temp = 0.14433756729740643f;  // 1/sqrt(48)
    for (int s = 0; s < 128; ++s) {
        float sc = 0.f;
        #pragma unroll
        for (int e = 0; e < 48; ++e) sc = fmaf(qr[e], Ks[s][e], sc);
        sc *= temp;
        float nm = fmaxf(m, sc);
        float alpha = __expf(m - nm);
        float p = __expf(sc - nm);
        denom = denom * alpha + p;
        #pragma unroll
        for (int e = 0; e < 48; ++e) acc[e] = fmaf(p, Vs[s][e], acc[e] * alpha);
        m = nm;
    }
    float inv = 1.f / denom;
    short* op = o + ((size_t)n * 128 + tid) * 384 + h * 48;
    #pragma unroll
    for (int e = 0; e < 48; ++e) op[e] = f2bf(acc[e] * inv);
}

// ---------------- LayerNorm (wave per row, D=384), dual output -------------
__global__ __launch_bounds__(256) void ln_kernel(
    const float* __restrict__ y, const float* __restrict__ g,
    const float* __restrict__ b, float* __restrict__ t, short* __restrict__ tb)
{
    int row = blockIdx.x * 4 + (threadIdx.x >> 6);
    int lane = threadIdx.x & 63;
    const float* yr = y + (size_t)row * 384;
    float vals[6];
    float s = 0.f, s2 = 0.f;
    #pragma unroll
    for (int mi = 0; mi < 6; ++mi) {
        float vv = yr[lane + mi * 64];
        vals[mi] = vv;
        s += vv;
        s2 = fmaf(vv, vv, s2);
    }
    #pragma unroll
    for (int off = 32; off > 0; off >>= 1) {
        s += __shfl_xor(s, off, 64);
        s2 += __shfl_xor(s2, off, 64);
    }
    float mean = s * (1.f / 384.f);
    float var = s2 * (1.f / 384.f) - mean * mean;
    float inv = rsqrtf(var + 1e-5f);
    float* tr = t + (size_t)row * 384;
    short* tbr = tb + (size_t)row * 384;
    #pragma unroll
    for (int mi = 0; mi < 6; ++mi) {
        int d = lane + mi * 64;
        float vv = (vals[mi] - mean) * inv * g[d] + b[d];
        tr[d] = vv;
        tbr[d] = f2bf(vv);
    }
}

// ---------------- classifier head ------------------------------------------
__global__ __launch_bounds__(384) void head_kernel(
    const float* __restrict__ t, const float* __restrict__ cls_w,
    const float* __restrict__ cls_b, float* __restrict__ out)
{
    int n = blockIdx.x, d = threadIdx.x;
    float s = 0.f;
    for (int l = 0; l < 128; ++l) s += t[((size_t)n * 128 + l) * 384 + d];
    float p = s * (1.f / 128.f) * cls_w[d];
    #pragma unroll
    for (int off = 32; off > 0; off >>= 1) p += __shfl_xor(p, off, 64);
    __shared__ float red[6];
    if ((threadIdx.x & 63) == 0) red[threadIdx.x >> 6] = p;
    __syncthreads();
    if (threadIdx.x == 0) {
        float tot = red[0] + red[1] + red[2] + red[3] + red[4] + red[5];
        out[n] = tot + cls_b[0];
    }
}

// ---------------------------------------------------------------------------
extern "C" void kernel_launch(void* const* d_in, const int* in_sizes, int n_in,
                              void* d_out, int out_size, void* d_ws, size_t ws_size,
                              hipStream_t stream) {
    (void)n_in; (void)out_size; (void)ws_size;
    const float* x   = (const float*)d_in[0];
    const float* cw0 = (const float*)d_in[1];
    const float* cb0 = (const float*)d_in[2];
    const float* cw1 = (const float*)d_in[3];
    const float* cb1 = (const float*)d_in[4];
    const float* cw2 = (const float*)d_in[5];
    const float* cb2 = (const float*)d_in[6];
    const float* ew  = (const float*)d_in[7];
    const float* eb  = (const float*)d_in[8];
    bool dict_order = (in_sizes[10] == 589824);
    const float *Wq, *Wk, *Wv, *Wo, *W1, *W2, *bq, *bk, *bv, *bo, *b1, *b2;
    if (dict_order) {
        Wq = (const float*)d_in[9];  Wk = (const float*)d_in[10];
        Wv = (const float*)d_in[11]; Wo = (const float*)d_in[12];
        W1 = (const float*)d_in[13]; W2 = (const float*)d_in[14];
        bq = (const float*)d_in[15]; bk = (const float*)d_in[16];
        bv = (const float*)d_in[17]; bo = (const float*)d_in[18];
        b1 = (const float*)d_in[19]; b2 = (const float*)d_in[20];
    } else {
        Wq = (const float*)d_in[9];  bq = (const float*)d_in[10];
        Wk = (const float*)d_in[11]; bk = (const float*)d_in[12];
        Wv = (const float*)d_in[13]; bv = (const float*)d_in[14];
        Wo = (const float*)d_in[15]; bo = (const float*)d_in[16];
        W1 = (const float*)d_in[17]; b1 = (const float*)d_in[18];
        W2 = (const float*)d_in[19]; b2 = (const float*)d_in[20];
    }
    const float* g1  = (const float*)d_in[21];
    const float* be1 = (const float*)d_in[22];
    const float* g2  = (const float*)d_in[23];
    const float* be2 = (const float*)d_in[24];
    const float* clw = (const float*)d_in[25];
    const float* clb = (const float*)d_in[26];

    // ---- workspace layout (bytes) ----
    char* wp = (char*)d_ws;
    float* pe    = (float*)wp; wp += 196608;      // 128*384 f32
    short* featb = (short*)wp; wp += 33554432;    // 8192*2048 bf16 (reused as FFN hidden)
    float* t     = (float*)wp; wp += 12582912;    // 8192*384 f32
    short* tb    = (short*)wp; wp += 6291456;     // 8192*384 bf16
    short* qkvb  = (short*)wp; wp += 18874368;    // 8192*1152 bf16
    short* ob    = (short*)wp; wp += 6291456;     // 8192*384 bf16 (attn out)
    float* y     = (float*)wp; wp += 12582912;    // pre-LN f32
    short* ewT   = (short*)wp; wp += 1572864;     // 384 x 2048
    short* WqkvT = (short*)wp; wp += 3538944;     // 4 x 1152 x 384
    short* WoT   = (short*)wp; wp += 1179648;     // 4 x 384 x 384
    short* W1T   = (short*)wp; wp += 4718592;     // 4 x 1536 x 384
    short* W2T   = (short*)wp; wp += 4718592;     // 4 x 384 x 1536
    float* bqkv  = (float*)wp; wp += 18432;       // 4 x 1152 f32
    short* hb    = featb;                         // FFN hidden 8192*1536 bf16

    const int ROWS = 8192;

    pe_kernel<<<128, 384, 0, stream>>>(pe);
    wcvt_kernel<<<dim3(64, 12, 1), 256, 0, stream>>>(ew, ewT, 2048, 384, 0, 0, 0);
    wcvt_kernel<<<dim3(12, 12, 4), 256, 0, stream>>>(Wq, WqkvT, 384, 384, 0, 147456, 442368);
    wcvt_kernel<<<dim3(12, 12, 4), 256, 0, stream>>>(Wk, WqkvT, 384, 384, 147456, 147456, 442368);
    wcvt_kernel<<<dim3(12, 12, 4), 256, 0, stream>>>(Wv, WqkvT, 384, 384, 294912, 147456, 442368);
    wcvt_kernel<<<dim3(12, 12, 4), 256, 0, stream>>>(Wo, WoT, 384, 384, 0, 147456, 147456);
    wcvt_kernel<<<dim3(12, 48, 4), 256, 0, stream>>>(W1, W1T, 384, 1536, 0, 589824, 589824);
    wcvt_kernel<<<dim3(48, 12, 4), 256, 0, stream>>>(W2, W2T, 1536, 384, 0, 589824, 589824);
    biascat_kernel<<<4, 384, 0, stream>>>(bq, bk, bv, bqkv);
    cnn_kernel<<<8192, 256, 0, stream>>>(x, cw0, cb0, cw1, cb1, cw2, cb2, featb);

    // t/tb = relu(feat @ ew + eb) + pe
    gemm_bf16<29><<<dim3(6, 128), 128, 0, stream>>>(featb, ewT, eb, nullptr, pe,
                                                    t, tb, ROWS, 384, 2048);
    for (int i = 0; i < 4; ++i) {
        const short* WqkvTi = WqkvT + (size_t)i * 442368;
        const short* WoTi = WoT + (size_t)i * 147456;
        const short* W1Ti = W1T + (size_t)i * 589824;
        const short* W2Ti = W2T + (size_t)i * 589824;
        // qkv = t @ [Wq|Wk|Wv] + [bq|bk|bv]
        gemm_bf16<16><<<dim3(18, 128), 128, 0, stream>>>(tb, WqkvTi, bqkv + i * 1152,
            nullptr, nullptr, nullptr, qkvb, ROWS, 1152, 384);
        attn_kernel<<<512, 128, 0, stream>>>(qkvb, ob);
        // y = o @ Wo + bo + t
        gemm_bf16<10><<<dim3(6, 128), 128, 0, stream>>>(ob, WoTi, bo + i * 384,
            t, nullptr, y, nullptr, ROWS, 384, 384);
        ln_kernel<<<2048, 256, 0, stream>>>(y, g1 + i * 384, be1 + i * 384, t, tb);
        // hidden = relu(t @ W1 + b1)
        gemm_bf16<17><<<dim3(24, 128), 128, 0, stream>>>(tb, W1Ti, b1 + i * 1536,
            nullptr, nullptr, nullptr, hb, ROWS, 1536, 384);
        // y = hidden @ W2 + b2 + t
        gemm_bf16<10><<<dim3(6, 128), 128, 0, stream>>>(hb, W2Ti, b2 + i * 384,
            t, nullptr, y, nullptr, ROWS, 384, 1536);
        ln_kernel<<<2048, 256, 0, stream>>>(y, g2 + i * 384, be2 + i * 384, t, tb);
    }
    head_kernel<<<64, 384, 0, stream>>>(t, clw, clb, (float*)d_out);
}

// Round 4
// 976.686 us; speedup vs baseline: 2.6123x; 1.0597x over previous
//
#include <hip/hip_runtime.h>
#include <math.h>

// ---------------------------------------------------------------------------
// N=64, L=128, W=256, D=384, H=8, E=48, NL=4, DFF=1536, rows = N*L = 8192
// GEMMs: bf16 MFMA 16x16x32, A [M][K] bf16 row-major, Bt [N][K] bf16.
// ---------------------------------------------------------------------------

typedef float f32x4 __attribute__((ext_vector_type(4)));
typedef short bf16x8 __attribute__((ext_vector_type(8)));
typedef short s16x4 __attribute__((ext_vector_type(4)));

__device__ __forceinline__ short f2bf(float f) {
    union { float f; unsigned u; } c; c.f = f;
    unsigned r = (c.u + 0x7FFFu + ((c.u >> 16) & 1u)) >> 16;
    return (short)r;
}
__device__ __forceinline__ float bf2f(short s) {
    union { unsigned u; float f; } c;
    c.u = ((unsigned)(unsigned short)s) << 16;
    return c.f;
}

__device__ __forceinline__ void gload_lds16(const void* g, void* l) {
    __builtin_amdgcn_global_load_lds(
        (const __attribute__((address_space(1))) unsigned int*)g,
        (__attribute__((address_space(3))) unsigned int*)l,
        16, 0, 0);
}

// ---------------- positional encoding table: pe[l][d] ----------------------
__global__ __launch_bounds__(384) void pe_kernel(float* __restrict__ pe) {
    int l = blockIdx.x, d = threadIdx.x;
    int i2 = d >> 1;
    float ang = (float)l * expf(-(2.0f * (float)i2 / 384.0f) * 9.210340371976184f);
    pe[l * 384 + d] = (d & 1) ? cosf(ang) : sinf(ang);
}

// ---------------- weight convert+transpose: W fp32 [K][N] -> bf16 [N][K] ---
__global__ __launch_bounds__(256) void wcvt_kernel(
    const float* __restrict__ W, short* __restrict__ Wt, int K, int N,
    int dstOff, int srcZ, int dstZ)
{
    __shared__ float tile[32][33];
    int kb = blockIdx.x * 32, nb = blockIdx.y * 32;
    const float* Wp = W + (size_t)blockIdx.z * srcZ;
    short* Wtp = Wt + (size_t)blockIdx.z * dstZ + dstOff;
    int tx = threadIdx.x & 31, ty = threadIdx.x >> 5;
    #pragma unroll
    for (int r = ty; r < 32; r += 8)
        tile[r][tx] = Wp[(size_t)(kb + r) * N + nb + tx];
    __syncthreads();
    #pragma unroll
    for (int r = ty; r < 32; r += 8)
        Wtp[(size_t)(nb + r) * K + kb + tx] = f2bf(tile[tx][r]);
}

// ---------------- concatenated qkv bias: bqkv[l][1152] ---------------------
__global__ __launch_bounds__(384) void biascat_kernel(
    const float* __restrict__ bq, const float* __restrict__ bk,
    const float* __restrict__ bv, float* __restrict__ bqkv)
{
    int l = blockIdx.x, j = threadIdx.x;
    bqkv[l * 1152 + j] = bq[l * 384 + j];
    bqkv[l * 1152 + 384 + j] = bk[l * 384 + j];
    bqkv[l * 1152 + 768 + j] = bv[l * 384 + j];
}

// ---------------- fused CNN window encoder (bf16 out) ----------------------
// One block per window; conv+relu+pool fused per stage. LDS strides chosen
// for conflict-free access:
//   p0 stride 136 -> write bank (8c+p)%32 uniform 2-way (free)
//   w2s [16][7][65] -> staging writes walk banks consecutively (2-way free),
//                      stage-C reads +c also 2-way free
__global__ __launch_bounds__(256) void cnn_kernel(
    const float* __restrict__ x,
    const float* __restrict__ w0, const float* __restrict__ b0,
    const float* __restrict__ w1, const float* __restrict__ b1,
    const float* __restrict__ w2, const float* __restrict__ b2,
    short* __restrict__ feat)
{
    __shared__ float xs[256];
    __shared__ float p0[4][136];
    __shared__ float p1[16][65];
    __shared__ float w2s[16][7][65];   // [ci][k][c], padded
    __shared__ float w1s[64][7];       // [(c*4+ci)][k]
    __shared__ float w0s[4][7];

    int tid = threadIdx.x;
    int win = blockIdx.x;

    xs[tid] = x[(size_t)win * 256 + tid];
    if (tid < 28) ((float*)w0s)[tid] = w0[tid];
    if (tid < 64) {
        for (int k = 0; k < 7; ++k) w1s[tid][k] = w1[tid * 7 + k];
    }
    for (int idx = tid; idx < 7168; idx += 256) {
        int c = idx / 112;
        int r = idx - c * 112;
        int ci = r / 7;
        int k = r - ci * 7;
        w2s[ci][k][c] = w2[idx];
    }
    __syncthreads();

    // ---- stage A: conv0 (1->4) + relu + pool2 -> p0[4][128] ----
    {
        int c = tid & 3, p = tid >> 2;      // p in 0..63
        float bb = b0[c];
        #pragma unroll
        for (int t2 = 0; t2 < 2; ++t2) {
            int pp = p + 64 * t2;           // pooled position 0..127
            float rv[9];
            #pragma unroll
            for (int u = 0; u < 9; ++u) {
                int j = 2 * pp + u - 3;
                rv[u] = (j >= 0 && j < 256) ? xs[j] : 0.f;
            }
            float a0 = bb, a1 = bb;
            #pragma unroll
            for (int k = 0; k < 7; ++k) {
                float w = w0s[c][k];
                a0 = fmaf(w, rv[k], a0);
                a1 = fmaf(w, rv[k + 1], a1);
            }
            p0[c][pp] = fmaxf(fmaxf(a0, a1), 0.f);
        }
    }
    __syncthreads();

    // ---- stage B: conv1 (4->16) + relu + pool2 -> p1[16][64] ----
    {
        int c = tid & 15;
        int i0 = (tid >> 4) * 8;            // conv positions i0..i0+7
        float acc[8];
        float bb = b1[c];
        #pragma unroll
        for (int m = 0; m < 8; ++m) acc[m] = bb;
        #pragma unroll
        for (int ci = 0; ci < 4; ++ci) {
            float rv[14];
            #pragma unroll
            for (int u = 0; u < 14; ++u) {
                int j = i0 + u - 3;
                rv[u] = (j >= 0 && j < 128) ? p0[ci][j] : 0.f;
            }
            #pragma unroll
            for (int k = 0; k < 7; ++k) {
                float w = w1s[c * 4 + ci][k];
                #pragma unroll
                for (int m = 0; m < 8; ++m) acc[m] = fmaf(w, rv[m + k], acc[m]);
            }
        }
        int po = i0 >> 1;                   // pooled positions po..po+3
        #pragma unroll
        for (int m = 0; m < 4; ++m)
            p1[c][po + m] = fmaxf(fmaxf(acc[2 * m], acc[2 * m + 1]), 0.f);
    }
    __syncthreads();

    // ---- stage C: conv2 (16->64) + relu + pool2 -> feat (bf16) ----
    {
        int c = tid & 63;                   // out channel
        int i0 = (tid >> 6) * 16;           // conv positions i0..i0+15
        float acc[16];
        float bb = b2[c];
        #pragma unroll
        for (int m = 0; m < 16; ++m) acc[m] = bb;
        for (int ci = 0; ci < 16; ++ci) {
            float rv[22];
            #pragma unroll
            for (int u = 0; u < 22; ++u) {
                int j = i0 + u - 3;
                rv[u] = (j >= 0 && j < 64) ? p1[ci][j] : 0.f;
            }
            #pragma unroll
            for (int k = 0; k < 7; ++k) {
                float w = w2s[ci][k][c];
                #pragma unroll
                for (int m = 0; m < 16; ++m) acc[m] = fmaf(w, rv[m + k], acc[m]);
            }
        }
        int po = i0 >> 1;                   // pooled 8 outputs
        short* fp = feat + (size_t)win * 2048 + c * 32 + po;
        #pragma unroll
        for (int m = 0; m < 8; ++m)
            fp[m] = f2bf(fmaxf(fmaxf(acc[2 * m], acc[2 * m + 1]), 0.f));
    }
}

// ---------------- bf16 MFMA GEMM: C = A[M][K] * Bt[N][K]^T -----------------
// BM=128, BN=64, BK=64; 256 threads = 4 waves (2 row-waves x 2 col-waves);
// each wave: 64 rows x 32 cols = 4x2 frags of 16x16x32.
// XOR-swizzled LDS (slot ^= row&7), global_load_lds width 16.
// EPI bits: 1=relu, 2=+resid(f32), 4=+pe, 8=write f32, 16=write bf16
template <int EPI>
__global__ __launch_bounds__(256) void gemm_bf16(
    const short* __restrict__ A, const short* __restrict__ Bt,
    const float* __restrict__ bias, const float* __restrict__ resid,
    const float* __restrict__ pe, float* __restrict__ outF,
    short* __restrict__ outB, int M, int N, int K)
{
    __shared__ short As[128 * 64];
    __shared__ short Bs[64 * 64];
    int tid = threadIdx.x;
    int w = tid >> 6, lane = tid & 63;
    int wm = w >> 1, wn = w & 1;
    int m0 = blockIdx.y * 128, n0 = blockIdx.x * 64;

    int rl = lane >> 3, sl = lane & 7;
    int cb = sl ^ rl;                    // staged rows are r ≡ rl (mod 8)
    const short* aptr[4];
    const short* bptr[2];
    int arow[4], brow[2];
    #pragma unroll
    for (int l = 0; l < 4; ++l) {
        arow[l] = l * 32 + w * 8;
        aptr[l] = A + (size_t)(m0 + arow[l] + rl) * K + cb * 8;
    }
    #pragma unroll
    for (int l = 0; l < 2; ++l) {
        brow[l] = l * 32 + w * 8;
        bptr[l] = Bt + (size_t)(n0 + brow[l] + rl) * K + cb * 8;
    }

    int cq = lane >> 4, cl = lane & 15;
    f32x4 acc[4][2];
    #pragma unroll
    for (int mt = 0; mt < 4; ++mt)
        #pragma unroll
        for (int nt = 0; nt < 2; ++nt)
            acc[mt][nt] = (f32x4){0.f, 0.f, 0.f, 0.f};

    for (int k0 = 0; k0 < K; k0 += 64) {
        #pragma unroll
        for (int l = 0; l < 4; ++l) {
            gload_lds16(aptr[l], &As[arow[l] * 64]);
            aptr[l] += 64;
        }
        #pragma unroll
        for (int l = 0; l < 2; ++l) {
            gload_lds16(bptr[l], &Bs[brow[l] * 64]);
            bptr[l] += 64;
        }
        __syncthreads();
        #pragma unroll
        for (int s = 0; s < 2; ++s) {
            bf16x8 af[4], bfr[2];
            #pragma unroll
            for (int mt = 0; mt < 4; ++mt) {
                int r = wm * 64 + mt * 16 + cl;
                int slot = (s * 4 + cq) ^ (r & 7);
                af[mt] = *(const bf16x8*)&As[r * 64 + slot * 8];
            }
            #pragma unroll
            for (int nt = 0; nt < 2; ++nt) {
                int r = wn * 32 + nt * 16 + cl;
                int slot = (s * 4 + cq) ^ (r & 7);
                bfr[nt] = *(const bf16x8*)&Bs[r * 64 + slot * 8];
            }
            #pragma unroll
            for (int mt = 0; mt < 4; ++mt)
                #pragma unroll
                for (int nt = 0; nt < 2; ++nt)
                    acc[mt][nt] = __builtin_amdgcn_mfma_f32_16x16x32_bf16(
                        af[mt], bfr[nt], acc[mt][nt], 0, 0, 0);
        }
        __syncthreads();
    }

    #pragma unroll
    for (int mt = 0; mt < 4; ++mt) {
        #pragma unroll
        for (int nt = 0; nt < 2; ++nt) {
            int col = n0 + wn * 32 + nt * 16 + cl;
            float bb = bias[col];
            #pragma unroll
            for (int rg = 0; rg < 4; ++rg) {
                int row = m0 + wm * 64 + mt * 16 + cq * 4 + rg;
                float v = acc[mt][nt][rg] + bb;
                if (EPI & 1) v = fmaxf(v, 0.f);
                if (EPI & 4) v += pe[(row & 127) * 384 + col];
                if (EPI & 2) v += resid[(size_t)row * N + col];
                if (EPI & 8) outF[(size_t)row * N + col] = v;
                if (EPI & 16) outB[(size_t)row * N + col] = f2bf(v);
            }
        }
    }
}

// ---------------- fused attention per (n,h), qkv packed [rows][1152] -------
__global__ __launch_bounds__(128) void attn_kernel(
    const short* __restrict__ qkv, short* __restrict__ o)
{
    __shared__ float Ks[128][48];
    __shared__ float Vs[128][48];
    int tid = threadIdx.x;
    int n = blockIdx.x >> 3, h = blockIdx.x & 7;
    size_t base = (size_t)n * 128 * 1152 + (size_t)h * 48;
    const short* kp = qkv + base + 384;
    const short* vp = qkv + base + 768;
    for (int i = tid; i < 1536; i += 128) {
        int s = i / 12, e4 = (i - s * 12) * 4;
        s16x4 kv = *(const s16x4*)(kp + (size_t)s * 1152 + e4);
        s16x4 vv = *(const s16x4*)(vp + (size_t)s * 1152 + e4);
        #pragma unroll
        for (int j = 0; j < 4; ++j) {
            Ks[s][e4 + j] = bf2f(kv[j]);
            Vs[s][e4 + j] = bf2f(vv[j]);
        }
    }
    float qr[48];
    {
        const short* qp = qkv + base + (size_t)tid * 1152;
        #pragma unroll
        for (int e4 = 0; e4 < 12; ++e4) {
            s16x4 qv = *(const s16x4*)(qp + e4 * 4);
            #pragma unroll
            for (int j = 0; j < 4; ++j) qr[e4 * 4 + j] = bf2f(qv[j]);
        }
    }
    __syncthreads();

    float m = -1e30f, denom = 0.f;
    float acc[48];
    #pragma unroll
    for (int e = 0; e < 48; ++e) acc[e] = 0.f;
    const float temp = 0.14433756729740643f;  // 1/sqrt(48)
    for (int s = 0; s < 128; ++s) {
        float sc = 0.f;
        #pragma unroll
        for (int e = 0; e < 48; ++e) sc = fmaf(qr[e], Ks[s][e], sc);
        sc *= temp;
        float nm = fmaxf(m, sc);
        float alpha = __expf(m - nm);
        float p = __expf(sc - nm);
        denom = denom * alpha + p;
        #pragma unroll
        for (int e = 0; e < 48; ++e) acc[e] = fmaf(p, Vs[s][e], acc[e] * alpha);
        m = nm;
    }
    float inv = 1.f / denom;
    short* op = o + ((size_t)n * 128 + tid) * 384 + h * 48;
    #pragma unroll
    for (int e = 0; e < 48; ++e) op[e] = f2bf(acc[e] * inv);
}

// ---------------- LayerNorm (wave per row, D=384), dual output -------------
__global__ __launch_bounds__(256) void ln_kernel(
    const float* __restrict__ y, const float* __restrict__ g,
    const float* __restrict__ b, float* __restrict__ t, short* __restrict__ tb)
{
    int row = blockIdx.x * 4 + (threadIdx.x >> 6);
    int lane = threadIdx.x & 63;
    const float* yr = y + (size_t)row * 384;
    float vals[6];
    float s = 0.f, s2 = 0.f;
    #pragma unroll
    for (int mi = 0; mi < 6; ++mi) {
        float vv = yr[lane + mi * 64];
        vals[mi] = vv;
        s += vv;
        s2 = fmaf(vv, vv, s2);
    }
    #pragma unroll
    for (int off = 32; off > 0; off >>= 1) {
        s += __shfl_xor(s, off, 64);
        s2 += __shfl_xor(s2, off, 64);
    }
    float mean = s * (1.f / 384.f);
    float var = s2 * (1.f / 384.f) - mean * mean;
    float inv = rsqrtf(var + 1e-5f);
    float* tr = t + (size_t)row * 384;
    short* tbr = tb + (size_t)row * 384;
    #pragma unroll
    for (int mi = 0; mi < 6; ++mi) {
        int d = lane + mi * 64;
        float vv = (vals[mi] - mean) * inv * g[d] + b[d];
        tr[d] = vv;
        tbr[d] = f2bf(vv);
    }
}

// ---------------- classifier head ------------------------------------------
__global__ __launch_bounds__(384) void head_kernel(
    const float* __restrict__ t, const float* __restrict__ cls_w,
    const float* __restrict__ cls_b, float* __restrict__ out)
{
    int n = blockIdx.x, d = threadIdx.x;
    float s = 0.f;
    for (int l = 0; l < 128; ++l) s += t[((size_t)n * 128 + l) * 384 + d];
    float p = s * (1.f / 128.f) * cls_w[d];
    #pragma unroll
    for (int off = 32; off > 0; off >>= 1) p += __shfl_xor(p, off, 64);
    __shared__ float red[6];
    if ((threadIdx.x & 63) == 0) red[threadIdx.x >> 6] = p;
    __syncthreads();
    if (threadIdx.x == 0) {
        float tot = red[0] + red[1] + red[2] + red[3] + red[4] + red[5];
        out[n] = tot + cls_b[0];
    }
}

// ---------------------------------------------------------------------------
extern "C" void kernel_launch(void* const* d_in, const int* in_sizes, int n_in,
                              void* d_out, int out_size, void* d_ws, size_t ws_size,
                              hipStream_t stream) {
    (void)n_in; (void)out_size; (void)ws_size;
    const float* x   = (const float*)d_in[0];
    const float* cw0 = (const float*)d_in[1];
    const float* cb0 = (const float*)d_in[2];
    const float* cw1 = (const float*)d_in[3];
    const float* cb1 = (const float*)d_in[4];
    const float* cw2 = (const float*)d_in[5];
    const float* cb2 = (const float*)d_in[6];
    const float* ew  = (const float*)d_in[7];
    const float* eb  = (const float*)d_in[8];
    bool dict_order = (in_sizes[10] == 589824);
    const float *Wq, *Wk, *Wv, *Wo, *W1, *W2, *bq, *bk, *bv, *bo, *b1, *b2;
    if (dict_order) {
        Wq = (const float*)d_in[9];  Wk = (const float*)d_in[10];
        Wv = (const float*)d_in[11]; Wo = (const float*)d_in[12];
        W1 = (const float*)d_in[13]; W2 = (const float*)d_in[14];
        bq = (const float*)d_in[15]; bk = (const float*)d_in[16];
        bv = (const float*)d_in[17]; bo = (const float*)d_in[18];
        b1 = (const float*)d_in[19]; b2 = (const float*)d_in[20];
    } else {
        Wq = (const float*)d_in[9];  bq = (const float*)d_in[10];
        Wk = (const float*)d_in[11]; bk = (const float*)d_in[12];
        Wv = (const float*)d_in[13]; bv = (const float*)d_in[14];
        Wo = (const float*)d_in[15]; bo = (const float*)d_in[16];
        W1 = (const float*)d_in[17]; b1 = (const float*)d_in[18];
        W2 = (const float*)d_in[19]; b2 = (const float*)d_in[20];
    }
    const float* g1  = (const float*)d_in[21];
    const float* be1 = (const float*)d_in[22];
    const float* g2  = (const float*)d_in[23];
    const float* be2 = (const float*)d_in[24];
    const float* clw = (const float*)d_in[25];
    const float* clb = (const float*)d_in[26];

    // ---- workspace layout (bytes) ----
    char* wp = (char*)d_ws;
    float* pe    = (float*)wp; wp += 196608;      // 128*384 f32
    short* featb = (short*)wp; wp += 33554432;    // 8192*2048 bf16 (reused as FFN hidden)
    float* t     = (float*)wp; wp += 12582912;    // 8192*384 f32
    short* tb    = (short*)wp; wp += 6291456;     // 8192*384 bf16
    short* qkvb  = (short*)wp; wp += 18874368;    // 8192*1152 bf16
    short* ob    = (short*)wp; wp += 6291456;     // 8192*384 bf16 (attn out)
    float* y     = (float*)wp; wp += 12582912;    // pre-LN f32
    short* ewT   = (short*)wp; wp += 1572864;     // 384 x 2048
    short* WqkvT = (short*)wp; wp += 3538944;     // 4 x 1152 x 384
    short* WoT   = (short*)wp; wp += 1179648;     // 4 x 384 x 384
    short* W1T   = (short*)wp; wp += 4718592;     // 4 x 1536 x 384
    short* W2T   = (short*)wp; wp += 4718592;     // 4 x 384 x 1536
    float* bqkv  = (float*)wp; wp += 18432;       // 4 x 1152 f32
    short* hb    = featb;                         // FFN hidden 8192*1536 bf16

    const int ROWS = 8192;

    pe_kernel<<<128, 384, 0, stream>>>(pe);
    wcvt_kernel<<<dim3(64, 12, 1), 256, 0, stream>>>(ew, ewT, 2048, 384, 0, 0, 0);
    wcvt_kernel<<<dim3(12, 12, 4), 256, 0, stream>>>(Wq, WqkvT, 384, 384, 0, 147456, 442368);
    wcvt_kernel<<<dim3(12, 12, 4), 256, 0, stream>>>(Wk, WqkvT, 384, 384, 147456, 147456, 442368);
    wcvt_kernel<<<dim3(12, 12, 4), 256, 0, stream>>>(Wv, WqkvT, 384, 384, 294912, 147456, 442368);
    wcvt_kernel<<<dim3(12, 12, 4), 256, 0, stream>>>(Wo, WoT, 384, 384, 0, 147456, 147456);
    wcvt_kernel<<<dim3(12, 48, 4), 256, 0, stream>>>(W1, W1T, 384, 1536, 0, 589824, 589824);
    wcvt_kernel<<<dim3(48, 12, 4), 256, 0, stream>>>(W2, W2T, 1536, 384, 0, 589824, 589824);
    biascat_kernel<<<4, 384, 0, stream>>>(bq, bk, bv, bqkv);
    cnn_kernel<<<8192, 256, 0, stream>>>(x, cw0, cb0, cw1, cb1, cw2, cb2, featb);

    // t/tb = relu(feat @ ew + eb) + pe
    gemm_bf16<29><<<dim3(6, 64), 256, 0, stream>>>(featb, ewT, eb, nullptr, pe,
                                                   t, tb, ROWS, 384, 2048);
    for (int i = 0; i < 4; ++i) {
        const short* WqkvTi = WqkvT + (size_t)i * 442368;
        const short* WoTi = WoT + (size_t)i * 147456;
        const short* W1Ti = W1T + (size_t)i * 589824;
        const short* W2Ti = W2T + (size_t)i * 589824;
        // qkv = t @ [Wq|Wk|Wv] + [bq|bk|bv]
        gemm_bf16<16><<<dim3(18, 64), 256, 0, stream>>>(tb, WqkvTi, bqkv + i * 1152,
            nullptr, nullptr, nullptr, qkvb, ROWS, 1152, 384);
        attn_kernel<<<512, 128, 0, stream>>>(qkvb, ob);
        // y = o @ Wo + bo + t
        gemm_bf16<10><<<dim3(6, 64), 256, 0, stream>>>(ob, WoTi, bo + i * 384,
            t, nullptr, y, nullptr, ROWS, 384, 384);
        ln_kernel<<<2048, 256, 0, stream>>>(y, g1 + i * 384, be1 + i * 384, t, tb);
        // hidden = relu(t @ W1 + b1)
        gemm_bf16<17><<<dim3(24, 64), 256, 0, stream>>>(tb, W1Ti, b1 + i * 1536,
            nullptr, nullptr, nullptr, hb, ROWS, 1536, 384);
        // y = hidden @ W2 + b2 + t
        gemm_bf16<10><<<dim3(6, 64), 256, 0, stream>>>(hb, W2Ti, b2 + i * 384,
            t, nullptr, y, nullptr, ROWS, 384, 1536);
        ln_kernel<<<2048, 256, 0, stream>>>(y, g2 + i * 384, be2 + i * 384, t, tb);
    }
    head_kernel<<<64, 384, 0, stream>>>(t, clw, clb, (float*)d_out);
}